// Round 19
// baseline (346.135 us; speedup 1.0000x reference)
//
#include <hip/hip_runtime.h>
#include <stdint.h>
#include <stddef.h>

#define BB 2
#define LL 2048
#define DD 1024
#define HH 16
#define DHH 64
#define NH 1024  // H*DH

typedef __attribute__((ext_vector_type(8))) __bf16 bf16x8;
typedef __attribute__((ext_vector_type(4))) float f32x4;

__device__ __forceinline__ f32x4 mfma_bf16(bf16x8 a, bf16x8 b, f32x4 c) {
    return __builtin_amdgcn_mfma_f32_16x16x32_bf16(a, b, c, 0, 0, 0);
}

__device__ __forceinline__ unsigned short f2bf(float f) {
    union { float f; unsigned u; } v; v.f = f;
    unsigned r = v.u + 0x7FFFu + ((v.u >> 16) & 1u);  // RNE
    return (unsigned short)(r >> 16);
}

__device__ __forceinline__ float bf2f(unsigned short s) {
    union { unsigned u; float f; } v; v.u = ((unsigned)s) << 16;
    return v.f;
}

__device__ __forceinline__ bf16x8 ld_frag(const unsigned short* p) {
    return *reinterpret_cast<const bf16x8*>(p);
}

// ---------------------------------------------------------------------------
// x [4096][1024] fp32 -> bf16 flat.
// ---------------------------------------------------------------------------
__global__ __launch_bounds__(256)
void conv_x_kernel(const float* __restrict__ x, unsigned short* __restrict__ xb)
{
    const size_t i = ((size_t)blockIdx.x * 256 + threadIdx.x) * 8;
    float4 a = *(const float4*)(x + i);
    float4 b = *(const float4*)(x + i + 4);
    unsigned short t[8];
    t[0] = f2bf(a.x); t[1] = f2bf(a.y); t[2] = f2bf(a.z); t[3] = f2bf(a.w);
    t[4] = f2bf(b.x); t[5] = f2bf(b.y); t[6] = f2bf(b.z); t[7] = f2bf(b.w);
    *(int4*)(xb + i) = *(const int4*)t;
}

// ---------------------------------------------------------------------------
// W [K=1024][N=1024] fp32 -> W^T [N][K] bf16. blockIdx.z selects Wq/Wk/Wv/Wo.
// ---------------------------------------------------------------------------
__global__ __launch_bounds__(256)
void conv_w_kernel(const float* __restrict__ W0, const float* __restrict__ W1,
                   const float* __restrict__ W2, const float* __restrict__ W3,
                   unsigned short* __restrict__ Wqkvt,
                   unsigned short* __restrict__ Wot)
{
    __shared__ unsigned short Ls[64][72];
    const int which = blockIdx.z;
    const float* W = (which == 0) ? W0 : (which == 1) ? W1 : (which == 2) ? W2 : W3;
    unsigned short* Wt = (which == 3) ? Wot : (Wqkvt + (size_t)which * 1024 * 1024);

    const int kt = blockIdx.x * 64, nt = blockIdx.y * 64;
    const int tid = threadIdx.x;

    {
        const int r = tid >> 2, c = (tid & 3) * 16;
        const float* wp = W + (size_t)(kt + r) * 1024 + nt + c;
        unsigned short t[16];
#pragma unroll
        for (int q = 0; q < 4; ++q) {
            float4 f = *(const float4*)(wp + q * 4);
            t[q * 4 + 0] = f2bf(f.x); t[q * 4 + 1] = f2bf(f.y);
            t[q * 4 + 2] = f2bf(f.z); t[q * 4 + 3] = f2bf(f.w);
        }
        *(int4*)&Ls[r][c]     = *(const int4*)&t[0];
        *(int4*)&Ls[r][c + 8] = *(const int4*)&t[8];
    }
    __syncthreads();
    {
        const int nr = tid >> 2, kc = (tid & 3) * 16;
        unsigned short t[16];
#pragma unroll
        for (int m = 0; m < 16; ++m) t[m] = Ls[kc + m][nr];
        unsigned short* op = Wt + (size_t)(nt + nr) * 1024 + kt + kc;
        *(int4*)op       = *(const int4*)&t[0];
        *(int4*)(op + 8) = *(const int4*)&t[8];
    }
}

// ---------------------------------------------------------------------------
// 128x128 tile bf16 GEMM (K=1024, BK=64), A [M][K] bf16, Bt [N][K] bf16.
// MODE 0: qkv epilogue + attn upper-triangle zero-fill (overlaps the 260 MB
//         of zero writes under this kernel's MFMA compute — qkv_gemm's HBM
//         write BW is otherwise idle). MODE 1: out epilogue.
// ---------------------------------------------------------------------------
template<int MODE>
__global__ __launch_bounds__(256)
void gemm128_kernel(const unsigned short* __restrict__ A,
                    const unsigned short* __restrict__ Bt,
                    const float* __restrict__ b0, const float* __restrict__ b1,
                    const float* __restrict__ b2,
                    void* __restrict__ outp,
                    float* __restrict__ attn_z)
{
    __shared__ __align__(16) unsigned short As[128][64];
    __shared__ __align__(16) unsigned short Bs[128][64];

    const int tid  = threadIdx.x;
    const int lane = tid & 63;
    const int w    = tid >> 6;
    const int wr   = w >> 1, wc = w & 1;
    const int l16  = lane & 15, lk = lane >> 4;

    const int m0 = blockIdx.y * 128;
    const int n0 = blockIdx.x * 128;

    const int r8  = tid >> 3;
    const int cb  = tid & 7;
    const int swz = cb ^ (r8 & 7);

    const unsigned short* Ap = A  + (size_t)m0 * 1024 + cb * 8;
    const unsigned short* Bp = Bt + (size_t)n0 * 1024 + cb * 8;

    f32x4 acc[4][4];
#pragma unroll
    for (int i = 0; i < 4; ++i)
#pragma unroll
        for (int j = 0; j < 4; ++j) acc[i][j] = f32x4{0.f, 0.f, 0.f, 0.f};

    for (int k0 = 0; k0 < 1024; k0 += 64) {
        __syncthreads();
#pragma unroll
        for (int c = 0; c < 4; ++c) {
            const int row = c * 32 + r8;
            bf16x8 av = ld_frag(Ap + (size_t)row * 1024 + k0);
            bf16x8 bv = ld_frag(Bp + (size_t)row * 1024 + k0);
            *(bf16x8*)&As[row][swz * 8] = av;
            *(bf16x8*)&Bs[row][swz * 8] = bv;
        }
        __syncthreads();

#pragma unroll
        for (int kk = 0; kk < 2; ++kk) {
            bf16x8 af[4], bfr[4];
#pragma unroll
            for (int fm = 0; fm < 4; ++fm) {
                const int row = wr * 64 + fm * 16 + l16;
                const int kb  = kk * 4 + lk;
                af[fm] = ld_frag(&As[row][(kb ^ (row & 7)) * 8]);
            }
#pragma unroll
            for (int fn = 0; fn < 4; ++fn) {
                const int row = wc * 64 + fn * 16 + l16;
                const int kb  = kk * 4 + lk;
                bfr[fn] = ld_frag(&Bs[row][(kb ^ (row & 7)) * 8]);
            }
#pragma unroll
            for (int fm = 0; fm < 4; ++fm)
#pragma unroll
                for (int fn = 0; fn < 4; ++fn)
                    acc[fm][fn] = mfma_bf16(af[fm], bfr[fn], acc[fm][fn]);
        }
    }

    if (MODE == 0) {
        const int which = n0 >> 10;
        const float* bias = (which == 0) ? b0 : (which == 1) ? b1 : b2;
        unsigned short* out = (unsigned short*)outp
                            + (size_t)which * ((size_t)BB * HH * LL * DHH);
        const int c00 = n0 & 1023;
#pragma unroll
        for (int fm = 0; fm < 4; ++fm)
#pragma unroll
            for (int fn = 0; fn < 4; ++fn)
#pragma unroll
                for (int r = 0; r < 4; ++r) {
                    const int grow = m0 + wr * 64 + fm * 16 + lk * 4 + r;
                    const int c    = c00 + wc * 64 + fn * 16 + l16;
                    const float v  = acc[fm][fn][r] + bias[c];
                    const int b = grow >> 11, i = grow & 2047;
                    const int h = c >> 6,     d = c & 63;
                    out[(((size_t)(b * HH + h)) * LL + i) * DHH + d] = f2bf(v);
                }

        // ---- attn upper-triangle zero-fill (input-independent; overlaps
        //      this kernel's MFMA). 1024 regions (bh, t): region = zero cols
        //      [ (t+1)*64, 2048 ) of attn rows [t*64, t*64+64) for head bh.
        //      768 blocks: bid handles region bid, and 768+bid if bid<256.
        const int bid = blockIdx.y * 24 + blockIdx.x;   // [0, 768)
#pragma unroll
        for (int rr = 0; rr < 2; ++rr) {
            if (rr == 1 && bid >= 256) break;
            const int reg = (rr == 0) ? bid : (768 + bid);
            const int bh = reg >> 5, t = reg & 31;
            const int zc0 = (t + 1) * 64;
            if (zc0 >= LL) continue;                    // t = 31: empty
            const int nz4 = (LL - zc0) >> 2;
            float* base = attn_z + ((size_t)bh * LL + t * 64) * LL + zc0;
            const f32x4 z4 = {0.f, 0.f, 0.f, 0.f};
            for (int row = 0; row < 64; ++row) {
                f32x4* zp = (f32x4*)(base + (size_t)row * LL);
                for (int c4 = tid; c4 < nz4; c4 += 256)
                    __builtin_nontemporal_store(z4, &zp[c4]);
            }
        }
    } else {
        float* out = (float*)outp;
#pragma unroll
        for (int fm = 0; fm < 4; ++fm)
#pragma unroll
            for (int fn = 0; fn < 4; ++fn)
#pragma unroll
                for (int r = 0; r < 4; ++r) {
                    const int grow = m0 + wr * 64 + fm * 16 + lk * 4 + r;
                    const int gcol = n0 + wc * 64 + fn * 16 + l16;
                    out[(size_t)grow * DD + gcol] = acc[fm][fn][r] + b0[gcol];
                }
    }
}

// ---------------------------------------------------------------------------
// V transpose: vws [bh][l][d] -> vT [bh][d][l].
// ---------------------------------------------------------------------------
__global__ __launch_bounds__(256)
void v_transpose_kernel(const unsigned short* __restrict__ vws,
                        unsigned short* __restrict__ vT)
{
    __shared__ unsigned short Ls[64][72];
    const int bh = blockIdx.y;
    const int i0 = blockIdx.x * 64;
    const int tid = threadIdx.x;

    {
        const int r = tid >> 2, c = (tid & 3) * 16;
        const unsigned short* vp = vws + ((size_t)bh * LL + i0 + r) * DHH + c;
        *(int4*)&Ls[r][c]     = *(const int4*)vp;
        *(int4*)&Ls[r][c + 8] = *(const int4*)(vp + 8);
    }
    __syncthreads();
    {
        const int d = tid >> 2, c = (tid & 3) * 16;
        unsigned short tmp[16];
#pragma unroll
        for (int m = 0; m < 16; ++m) tmp[m] = Ls[c + m][d];
        unsigned short* op = vT + ((size_t)bh * DHH + d) * LL + i0 + c;
        *(int4*)op       = *(const int4*)&tmp[0];
        *(int4*)(op + 8) = *(const int4*)&tmp[8];
    }
}

// ---------------------------------------------------------------------------
// Fused causal attention — R18 verbatim (304.9 µs) MINUS the zero-fill
// (moved into qkv_gemm where it overlaps MFMA compute).
// QBLK=32, 128 threads (2 waves), zero barriers, balanced grid, max-free
// softmax, Ps-readback coalesced attn store, __launch_bounds__(128,3).
// ---------------------------------------------------------------------------

#define LOADK(KB, JB) do {                                                     \
    const unsigned short* kt_ = kbase + (size_t)(JB) * 64 * DHH;               \
    _Pragma("unroll")                                                          \
    for (int fn = 0; fn < 4; ++fn) {                                           \
        KB[2 * fn]     = ld_frag(kt_ + (size_t)(fn * 16 + l16) * DHH + lk * 8);\
        KB[2 * fn + 1] = ld_frag(kt_ + (size_t)(fn * 16 + l16) * DHH + 32 + lk * 8);\
    }                                                                          \
} while (0)

#define ACCUMA(JB, KB) do {                                                    \
    float g_[16];                                                              \
    _Pragma("unroll")                                                          \
    for (int fn = 0; fn < 4; ++fn) {                                           \
        const float* gp_ = gbrow + (JB) * 64 + fn * 16 + l16;                  \
        _Pragma("unroll")                                                      \
        for (int r = 0; r < 4; ++r) g_[fn * 4 + r] = gp_[(size_t)r * LL];      \
    }                                                                          \
    f32x4 z_[4];                                                               \
    _Pragma("unroll")                                                          \
    for (int fn = 0; fn < 4; ++fn) {                                           \
        f32x4 z = {0.f, 0.f, 0.f, 0.f};                                        \
        z = mfma_bf16(qa0, KB[2 * fn], z);                                     \
        z = mfma_bf16(qa1, KB[2 * fn + 1], z);                                 \
        z_[fn] = z;                                                            \
    }                                                                          \
    _Pragma("unroll")                                                          \
    for (int fn = 0; fn < 4; ++fn) {                                           \
        const int gj_ = (JB) * 64 + fn * 16 + l16;                             \
        _Pragma("unroll")                                                      \
        for (int r = 0; r < 4; ++r) {                                          \
            const float sv_ = fmaf(z_[fn][r], 0.125f, lb + g_[fn * 4 + r]);    \
            s_run[r] += (gj_ > gi0 + r) ? 0.f : __expf(sv_);                   \
        }                                                                      \
    }                                                                          \
} while (0)

#define PASSB_BODY(JB, ...) do {                                               \
    bf16x8 vb_[8];                                                             \
    _Pragma("unroll")                                                          \
    for (int fn = 0; fn < 4; ++fn) {                                           \
        const unsigned short* vp_ = vtb + (size_t)(fn * 16 + l16) * LL + (JB) * 64;\
        vb_[2 * fn]     = ld_frag(vp_ + lk * 8);                               \
        vb_[2 * fn + 1] = ld_frag(vp_ + 32 + lk * 8);                          \
    }                                                                          \
    float g_[16];                                                              \
    _Pragma("unroll")                                                          \
    for (int fn = 0; fn < 4; ++fn) {                                           \
        const float* gp_ = gbrow + (JB) * 64 + fn * 16 + l16;                  \
        _Pragma("unroll")                                                      \
        for (int r = 0; r < 4; ++r) g_[fn * 4 + r] = gp_[(size_t)r * LL];      \
    }                                                                          \
    f32x4 z_[4];                                                               \
    _Pragma("unroll")                                                          \
    for (int fn = 0; fn < 4; ++fn) {                                           \
        f32x4 z = {0.f, 0.f, 0.f, 0.f};                                        \
        z = mfma_bf16(qa0, ka[2 * fn], z);                                     \
        z = mfma_bf16(qa1, ka[2 * fn + 1], z);                                 \
        z_[fn] = z;                                                            \
    }                                                                          \
    __VA_ARGS__;                                                               \
    _Pragma("unroll")                                                          \
    for (int fn = 0; fn < 4; ++fn) {                                           \
        const int gj_ = (JB) * 64 + fn * 16 + l16;                             \
        _Pragma("unroll")                                                      \
        for (int r = 0; r < 4; ++r) {                                          \
            const float sv_ = fmaf(z_[fn][r], 0.125f, lb + g_[fn * 4 + r]);    \
            const float p_ = ((gj_ > gi0 + r) ? 0.f : __expf(sv_)) * inv_s[r]; \
            Ps[w][lk * 4 + r][fn * 16 + l16] = f2bf(p_);                       \
        }                                                                      \
    }                                                                          \
    const int jc0_ = (JB) * 64 + l16 * 4;                                      \
    _Pragma("unroll")                                                          \
    for (int s = 0; s < 4; ++s) {                                              \
        const int row_ = s * 4 + lk;                                           \
        const int gi_  = i0 + w * 16 + row_;                                   \
        ushort4 pb_ = *(const ushort4*)&Ps[w][row_][l16 * 4];                  \
        f32x4 pv_;                                                             \
        pv_.x = bf2f(pb_.x); pv_.y = bf2f(pb_.y);                              \
        pv_.z = bf2f(pb_.z); pv_.w = bf2f(pb_.w);                              \
        __builtin_nontemporal_store(                                           \
            pv_, (f32x4*)&attn_out[((size_t)bhh * LL + gi_) * LL + jc0_]);     \
    }                                                                          \
    bf16x8 pa0_ = ld_frag(&Ps[w][l16][lk * 8]);                                \
    bf16x8 pa1_ = ld_frag(&Ps[w][l16][32 + lk * 8]);                           \
    _Pragma("unroll")                                                          \
    for (int fn = 0; fn < 4; ++fn) {                                           \
        oacc[fn] = mfma_bf16(pa0_, vb_[2 * fn], oacc[fn]);                     \
        oacc[fn] = mfma_bf16(pa1_, vb_[2 * fn + 1], oacc[fn]);                 \
    }                                                                          \
} while (0)

__global__ __launch_bounds__(128, 3)
void attn_kernel(const unsigned short* __restrict__ qws,
                 const unsigned short* __restrict__ kws,
                 const unsigned short* __restrict__ vT,
                 const float* __restrict__ B_graph,
                 const float* __restrict__ lattice,
                 const float* __restrict__ Wl,
                 const float* __restrict__ bl,
                 float* __restrict__ attn_out,
                 unsigned short* __restrict__ out_pre)
{
    const int n  = blockIdx.x;           // [0, 2048)
    const int bh = n & 31;
    const int tb = n >> 5;               // [0, 64)
    const int kg = tb >> 3, tt = tb & 7;
    const int ib = 8 * kg + ((kg & 1) ? 7 - tt : tt);
    const int b = bh >> 4, h = bh & 15;
    const int i0 = ib * 32;
    const int nj = (ib >> 1) + 1;

    __shared__ unsigned short Ps[2][16][72];

    const int tid  = threadIdx.x;
    const int lane = tid & 63;
    const int w    = tid >> 6;
    const int l16  = lane & 15, lk = lane >> 4;

    float lb = bl[h];
#pragma unroll
    for (int t = 0; t < 6; ++t) lb += lattice[b * 6 + t] * Wl[t * HH + h];

    const int bhh = b * HH + h;
    const unsigned short* qbase = qws + ((size_t)bhh * LL + i0) * DHH;
    const unsigned short* kbase = kws + (size_t)bhh * LL * DHH;
    const unsigned short* vtb   = vT + (size_t)bhh * DHH * LL;
    const float* gb = B_graph + (size_t)b * LL * LL;

    bf16x8 qa0 = ld_frag(qbase + (size_t)(w * 16 + l16) * DHH + lk * 8);
    bf16x8 qa1 = ld_frag(qbase + (size_t)(w * 16 + l16) * DHH + 32 + lk * 8);

    const int gi0 = i0 + w * 16 + lk * 4;  // + r
    const float* gbrow = gb + (size_t)gi0 * LL;

    float s_run[4];
#pragma unroll
    for (int r = 0; r < 4; ++r) s_run[r] = 0.f;

    // -------- pass A: K double-buffered, peeled pair loop --------
    {
        bf16x8 ka[8], kb[8];
        LOADK(ka, 0);
        int jb = 1;
        for (; jb + 1 < nj; jb += 2) {
            LOADK(kb, jb);
            ACCUMA(jb - 1, ka);
            LOADK(ka, jb + 1);
            ACCUMA(jb, kb);
        }
        if (jb < nj) {
            LOADK(kb, jb);
            ACCUMA(jb - 1, ka);
            ACCUMA(jb, kb);
        } else {
            ACCUMA(jb - 1, ka);
        }
    }
#pragma unroll
    for (int off = 1; off < 16; off <<= 1)
#pragma unroll
        for (int r = 0; r < 4; ++r) s_run[r] += __shfl_xor(s_run[r], off, 64);

    float inv_s[4];
#pragma unroll
    for (int r = 0; r < 4; ++r) inv_s[r] = 1.0f / s_run[r];

    f32x4 oacc[4];
#pragma unroll
    for (int fn = 0; fn < 4; ++fn) oacc[fn] = f32x4{0.f, 0.f, 0.f, 0.f};

    // -------- pass B: rotating single-buffer K prefetch --------
    {
        bf16x8 ka[8];
        LOADK(ka, 0);
        int jb = 0;
        for (; jb + 1 < nj; ++jb) {
            PASSB_BODY(jb, LOADK(ka, jb + 1));
        }
        PASSB_BODY(jb, );
    }

#pragma unroll
    for (int fn = 0; fn < 4; ++fn)
#pragma unroll
        for (int r = 0; r < 4; ++r) {
            const int gi = gi0 + r;
            const int d  = fn * 16 + l16;
            out_pre[((size_t)(b * LL + gi)) * NH + h * DHH + d] = f2bf(oacc[fn][r]);
        }
}

// ---------------------------------------------------------------------------
extern "C" void kernel_launch(void* const* d_in, const int* in_sizes, int n_in,
                              void* d_out, int out_size, void* d_ws, size_t ws_size,
                              hipStream_t stream)
{
    const float* x       = (const float*)d_in[0];
    const float* lattice = (const float*)d_in[1];
    const float* B_graph = (const float*)d_in[2];
    const float* Wq = (const float*)d_in[4];
    const float* bq = (const float*)d_in[5];
    const float* Wk = (const float*)d_in[6];
    const float* bk = (const float*)d_in[7];
    const float* Wv = (const float*)d_in[8];
    const float* bv = (const float*)d_in[9];
    const float* Wo = (const float*)d_in[10];
    const float* bo = (const float*)d_in[11];
    const float* Wl = (const float*)d_in[12];
    const float* bl = (const float*)d_in[13];

    float* out  = (float*)d_out;
    float* attn = out + (size_t)BB * LL * DD;

    const size_t PHL = (size_t)BB * HH * LL * DHH;
    unsigned short* qkv    = (unsigned short*)d_ws;
    unsigned short* qw     = qkv;
    unsigned short* kw     = qkv + PHL;
    unsigned short* vw     = qkv + 2 * PHL;
    unsigned short* outpre = qkv + 3 * PHL;
    unsigned short* Wqkvt  = outpre;                 // alias until attn runs
    unsigned short* xb     = outpre + (size_t)BB * LL * NH;
    unsigned short* vT     = xb;                     // alias after qkv GEMM
    unsigned short* Wot    = xb + (size_t)BB * LL * DD;

    conv_x_kernel<<<dim3((BB * LL * DD) / (256 * 8)), 256, 0, stream>>>(x, xb);
    conv_w_kernel<<<dim3(16, 16, 4), 256, 0, stream>>>(Wq, Wk, Wv, Wo, Wqkvt, Wot);

    gemm128_kernel<0><<<dim3(3 * NH / 128, (BB * LL) / 128), 256, 0, stream>>>(
        xb, Wqkvt, bq, bk, bv, qkv, attn);

    v_transpose_kernel<<<dim3(LL / 64, BB * HH), 256, 0, stream>>>(vw, vT);

    attn_kernel<<<dim3(BB * HH * (LL / 32)), 128, 0, stream>>>(
        qw, kw, vT, B_graph, lattice, Wl, bl, attn, outpre);

    gemm128_kernel<1><<<dim3(DD / 128, (BB * LL) / 128), 256, 0, stream>>>(
        outpre, Wot, bo, bo, bo, out, nullptr);
}

// Round 20
// 308.067 us; speedup vs baseline: 1.1236x; 1.1236x over previous
//
#include <hip/hip_runtime.h>
#include <stdint.h>
#include <stddef.h>

#define BB 2
#define LL 2048
#define DD 1024
#define HH 16
#define DHH 64
#define NH 1024  // H*DH

typedef __attribute__((ext_vector_type(8))) __bf16 bf16x8;
typedef __attribute__((ext_vector_type(4))) float f32x4;

__device__ __forceinline__ f32x4 mfma_bf16(bf16x8 a, bf16x8 b, f32x4 c) {
    return __builtin_amdgcn_mfma_f32_16x16x32_bf16(a, b, c, 0, 0, 0);
}

__device__ __forceinline__ unsigned short f2bf(float f) {
    union { float f; unsigned u; } v; v.f = f;
    unsigned r = v.u + 0x7FFFu + ((v.u >> 16) & 1u);  // RNE
    return (unsigned short)(r >> 16);
}

__device__ __forceinline__ float bf2f(unsigned short s) {
    union { unsigned u; float f; } v; v.u = ((unsigned)s) << 16;
    return v.f;
}

__device__ __forceinline__ bf16x8 ld_frag(const unsigned short* p) {
    return *reinterpret_cast<const bf16x8*>(p);
}

// ---------------------------------------------------------------------------
// x [4096][1024] fp32 -> bf16 flat.
// ---------------------------------------------------------------------------
__global__ __launch_bounds__(256)
void conv_x_kernel(const float* __restrict__ x, unsigned short* __restrict__ xb)
{
    const size_t i = ((size_t)blockIdx.x * 256 + threadIdx.x) * 8;
    float4 a = *(const float4*)(x + i);
    float4 b = *(const float4*)(x + i + 4);
    unsigned short t[8];
    t[0] = f2bf(a.x); t[1] = f2bf(a.y); t[2] = f2bf(a.z); t[3] = f2bf(a.w);
    t[4] = f2bf(b.x); t[5] = f2bf(b.y); t[6] = f2bf(b.z); t[7] = f2bf(b.w);
    *(int4*)(xb + i) = *(const int4*)t;
}

// ---------------------------------------------------------------------------
// W [K=1024][N=1024] fp32 -> W^T [N][K] bf16. blockIdx.z selects Wq/Wk/Wv/Wo.
// ---------------------------------------------------------------------------
__global__ __launch_bounds__(256)
void conv_w_kernel(const float* __restrict__ W0, const float* __restrict__ W1,
                   const float* __restrict__ W2, const float* __restrict__ W3,
                   unsigned short* __restrict__ Wqkvt,
                   unsigned short* __restrict__ Wot)
{
    __shared__ unsigned short Ls[64][72];
    const int which = blockIdx.z;
    const float* W = (which == 0) ? W0 : (which == 1) ? W1 : (which == 2) ? W2 : W3;
    unsigned short* Wt = (which == 3) ? Wot : (Wqkvt + (size_t)which * 1024 * 1024);

    const int kt = blockIdx.x * 64, nt = blockIdx.y * 64;
    const int tid = threadIdx.x;

    {
        const int r = tid >> 2, c = (tid & 3) * 16;
        const float* wp = W + (size_t)(kt + r) * 1024 + nt + c;
        unsigned short t[16];
#pragma unroll
        for (int q = 0; q < 4; ++q) {
            float4 f = *(const float4*)(wp + q * 4);
            t[q * 4 + 0] = f2bf(f.x); t[q * 4 + 1] = f2bf(f.y);
            t[q * 4 + 2] = f2bf(f.z); t[q * 4 + 3] = f2bf(f.w);
        }
        *(int4*)&Ls[r][c]     = *(const int4*)&t[0];
        *(int4*)&Ls[r][c + 8] = *(const int4*)&t[8];
    }
    __syncthreads();
    {
        const int nr = tid >> 2, kc = (tid & 3) * 16;
        unsigned short t[16];
#pragma unroll
        for (int m = 0; m < 16; ++m) t[m] = Ls[kc + m][nr];
        unsigned short* op = Wt + (size_t)(nt + nr) * 1024 + kt + kc;
        *(int4*)op       = *(const int4*)&t[0];
        *(int4*)(op + 8) = *(const int4*)&t[8];
    }
}

// ---------------------------------------------------------------------------
// 128x128 tile bf16 GEMM (K=1024, BK=64), A [M][K] bf16, Bt [N][K] bf16.
// MODE 0: qkv epilogue; MODE 1: out epilogue.   (R18 version — no zero-fill)
// ---------------------------------------------------------------------------
template<int MODE>
__global__ __launch_bounds__(256)
void gemm128_kernel(const unsigned short* __restrict__ A,
                    const unsigned short* __restrict__ Bt,
                    const float* __restrict__ b0, const float* __restrict__ b1,
                    const float* __restrict__ b2,
                    void* __restrict__ outp)
{
    __shared__ __align__(16) unsigned short As[128][64];
    __shared__ __align__(16) unsigned short Bs[128][64];

    const int tid  = threadIdx.x;
    const int lane = tid & 63;
    const int w    = tid >> 6;
    const int wr   = w >> 1, wc = w & 1;
    const int l16  = lane & 15, lk = lane >> 4;

    const int m0 = blockIdx.y * 128;
    const int n0 = blockIdx.x * 128;

    const int r8  = tid >> 3;
    const int cb  = tid & 7;
    const int swz = cb ^ (r8 & 7);

    const unsigned short* Ap = A  + (size_t)m0 * 1024 + cb * 8;
    const unsigned short* Bp = Bt + (size_t)n0 * 1024 + cb * 8;

    f32x4 acc[4][4];
#pragma unroll
    for (int i = 0; i < 4; ++i)
#pragma unroll
        for (int j = 0; j < 4; ++j) acc[i][j] = f32x4{0.f, 0.f, 0.f, 0.f};

    for (int k0 = 0; k0 < 1024; k0 += 64) {
        __syncthreads();
#pragma unroll
        for (int c = 0; c < 4; ++c) {
            const int row = c * 32 + r8;
            bf16x8 av = ld_frag(Ap + (size_t)row * 1024 + k0);
            bf16x8 bv = ld_frag(Bp + (size_t)row * 1024 + k0);
            *(bf16x8*)&As[row][swz * 8] = av;
            *(bf16x8*)&Bs[row][swz * 8] = bv;
        }
        __syncthreads();

#pragma unroll
        for (int kk = 0; kk < 2; ++kk) {
            bf16x8 af[4], bfr[4];
#pragma unroll
            for (int fm = 0; fm < 4; ++fm) {
                const int row = wr * 64 + fm * 16 + l16;
                const int kb  = kk * 4 + lk;
                af[fm] = ld_frag(&As[row][(kb ^ (row & 7)) * 8]);
            }
#pragma unroll
            for (int fn = 0; fn < 4; ++fn) {
                const int row = wc * 64 + fn * 16 + l16;
                const int kb  = kk * 4 + lk;
                bfr[fn] = ld_frag(&Bs[row][(kb ^ (row & 7)) * 8]);
            }
#pragma unroll
            for (int fm = 0; fm < 4; ++fm)
#pragma unroll
                for (int fn = 0; fn < 4; ++fn)
                    acc[fm][fn] = mfma_bf16(af[fm], bfr[fn], acc[fm][fn]);
        }
    }

    if (MODE == 0) {
        const int which = n0 >> 10;
        const float* bias = (which == 0) ? b0 : (which == 1) ? b1 : b2;
        unsigned short* out = (unsigned short*)outp
                            + (size_t)which * ((size_t)BB * HH * LL * DHH);
        const int c00 = n0 & 1023;
#pragma unroll
        for (int fm = 0; fm < 4; ++fm)
#pragma unroll
            for (int fn = 0; fn < 4; ++fn)
#pragma unroll
                for (int r = 0; r < 4; ++r) {
                    const int grow = m0 + wr * 64 + fm * 16 + lk * 4 + r;
                    const int c    = c00 + wc * 64 + fn * 16 + l16;
                    const float v  = acc[fm][fn][r] + bias[c];
                    const int b = grow >> 11, i = grow & 2047;
                    const int h = c >> 6,     d = c & 63;
                    out[(((size_t)(b * HH + h)) * LL + i) * DHH + d] = f2bf(v);
                }
    } else {
        float* out = (float*)outp;
#pragma unroll
        for (int fm = 0; fm < 4; ++fm)
#pragma unroll
            for (int fn = 0; fn < 4; ++fn)
#pragma unroll
                for (int r = 0; r < 4; ++r) {
                    const int grow = m0 + wr * 64 + fm * 16 + lk * 4 + r;
                    const int gcol = n0 + wc * 64 + fn * 16 + l16;
                    out[(size_t)grow * DD + gcol] = acc[fm][fn][r] + b0[gcol];
                }
    }
}

// ---------------------------------------------------------------------------
// V transpose: vws [bh][l][d] -> vT [bh][d][l].
// ---------------------------------------------------------------------------
__global__ __launch_bounds__(256)
void v_transpose_kernel(const unsigned short* __restrict__ vws,
                        unsigned short* __restrict__ vT)
{
    __shared__ unsigned short Ls[64][72];
    const int bh = blockIdx.y;
    const int i0 = blockIdx.x * 64;
    const int tid = threadIdx.x;

    {
        const int r = tid >> 2, c = (tid & 3) * 16;
        const unsigned short* vp = vws + ((size_t)bh * LL + i0 + r) * DHH + c;
        *(int4*)&Ls[r][c]     = *(const int4*)vp;
        *(int4*)&Ls[r][c + 8] = *(const int4*)(vp + 8);
    }
    __syncthreads();
    {
        const int d = tid >> 2, c = (tid & 3) * 16;
        unsigned short tmp[16];
#pragma unroll
        for (int m = 0; m < 16; ++m) tmp[m] = Ls[c + m][d];
        unsigned short* op = vT + ((size_t)bh * DHH + d) * LL + i0 + c;
        *(int4*)op       = *(const int4*)&tmp[0];
        *(int4*)(op + 8) = *(const int4*)&tmp[8];
    }
}

// ---------------------------------------------------------------------------
// Fused causal attention — R18 base (304.9 µs) with pass B converted to the
// pass-A-style PEELED PAIR loop: two tiles in flight (ka/kb K buffers), each
// body using its own PARITY-INDEXED Ps buffer (Ps[w][parity]) so the two
// in-flight P regions are disjoint — removes the R13 type-punned aliasing
// hazard (Ps written as u16, read as bf16x8/ushort4).
// QBLK=32, 128 threads (2 waves), zero barriers, balanced grid, max-free
// softmax, Ps-readback coalesced attn store, __launch_bounds__(128,3).
// ---------------------------------------------------------------------------

#define LOADK(KB, JB) do {                                                     \
    const unsigned short* kt_ = kbase + (size_t)(JB) * 64 * DHH;               \
    _Pragma("unroll")                                                          \
    for (int fn = 0; fn < 4; ++fn) {                                           \
        KB[2 * fn]     = ld_frag(kt_ + (size_t)(fn * 16 + l16) * DHH + lk * 8);\
        KB[2 * fn + 1] = ld_frag(kt_ + (size_t)(fn * 16 + l16) * DHH + 32 + lk * 8);\
    }                                                                          \
} while (0)

// pass-A accumulate for tile JB from buffer KB (R18 verbatim)
#define ACCUMA(JB, KB) do {                                                    \
    float g_[16];                                                              \
    _Pragma("unroll")                                                          \
    for (int fn = 0; fn < 4; ++fn) {                                           \
        const float* gp_ = gbrow + (JB) * 64 + fn * 16 + l16;                  \
        _Pragma("unroll")                                                      \
        for (int r = 0; r < 4; ++r) g_[fn * 4 + r] = gp_[(size_t)r * LL];      \
    }                                                                          \
    f32x4 z_[4];                                                               \
    _Pragma("unroll")                                                          \
    for (int fn = 0; fn < 4; ++fn) {                                           \
        f32x4 z = {0.f, 0.f, 0.f, 0.f};                                        \
        z = mfma_bf16(qa0, KB[2 * fn], z);                                     \
        z = mfma_bf16(qa1, KB[2 * fn + 1], z);                                 \
        z_[fn] = z;                                                            \
    }                                                                          \
    _Pragma("unroll")                                                          \
    for (int fn = 0; fn < 4; ++fn) {                                           \
        const int gj_ = (JB) * 64 + fn * 16 + l16;                             \
        _Pragma("unroll")                                                      \
        for (int r = 0; r < 4; ++r) {                                          \
            const float sv_ = fmaf(z_[fn][r], 0.125f, lb + g_[fn * 4 + r]);    \
            s_run[r] += (gj_ > gi0 + r) ? 0.f : __expf(sv_);                   \
        }                                                                      \
    }                                                                          \
} while (0)

// pass-B tile body for tile JB from K buffer KB, using Ps[w][PAR] (PAR is a
// compile-time constant 0/1 — the two in-flight bodies use disjoint buffers).
#define PASSB_BODY(JB, KB, PAR) do {                                           \
    bf16x8 vb_[8];                                                             \
    _Pragma("unroll")                                                          \
    for (int fn = 0; fn < 4; ++fn) {                                           \
        const unsigned short* vp_ = vtb + (size_t)(fn * 16 + l16) * LL + (JB) * 64;\
        vb_[2 * fn]     = ld_frag(vp_ + lk * 8);                               \
        vb_[2 * fn + 1] = ld_frag(vp_ + 32 + lk * 8);                          \
    }                                                                          \
    float g_[16];                                                              \
    _Pragma("unroll")                                                          \
    for (int fn = 0; fn < 4; ++fn) {                                           \
        const float* gp_ = gbrow + (JB) * 64 + fn * 16 + l16;                  \
        _Pragma("unroll")                                                      \
        for (int r = 0; r < 4; ++r) g_[fn * 4 + r] = gp_[(size_t)r * LL];      \
    }                                                                          \
    f32x4 z_[4];                                                               \
    _Pragma("unroll")                                                          \
    for (int fn = 0; fn < 4; ++fn) {                                           \
        f32x4 z = {0.f, 0.f, 0.f, 0.f};                                        \
        z = mfma_bf16(qa0, KB[2 * fn], z);                                     \
        z = mfma_bf16(qa1, KB[2 * fn + 1], z);                                 \
        z_[fn] = z;                                                            \
    }                                                                          \
    _Pragma("unroll")                                                          \
    for (int fn = 0; fn < 4; ++fn) {                                           \
        const int gj_ = (JB) * 64 + fn * 16 + l16;                             \
        _Pragma("unroll")                                                      \
        for (int r = 0; r < 4; ++r) {                                          \
            const float sv_ = fmaf(z_[fn][r], 0.125f, lb + g_[fn * 4 + r]);    \
            const float p_ = ((gj_ > gi0 + r) ? 0.f : __expf(sv_)) * inv_s[r]; \
            Ps[w][PAR][lk * 4 + r][fn * 16 + l16] = f2bf(p_);                  \
        }                                                                      \
    }                                                                          \
    const int jc0_ = (JB) * 64 + l16 * 4;                                      \
    _Pragma("unroll")                                                          \
    for (int s = 0; s < 4; ++s) {                                              \
        const int row_ = s * 4 + lk;                                           \
        const int gi_  = i0 + w * 16 + row_;                                   \
        ushort4 pb_ = *(const ushort4*)&Ps[w][PAR][row_][l16 * 4];             \
        f32x4 pv_;                                                             \
        pv_.x = bf2f(pb_.x); pv_.y = bf2f(pb_.y);                              \
        pv_.z = bf2f(pb_.z); pv_.w = bf2f(pb_.w);                              \
        __builtin_nontemporal_store(                                           \
            pv_, (f32x4*)&attn_out[((size_t)bhh * LL + gi_) * LL + jc0_]);     \
    }                                                                          \
    bf16x8 pa0_ = ld_frag(&Ps[w][PAR][l16][lk * 8]);                           \
    bf16x8 pa1_ = ld_frag(&Ps[w][PAR][l16][32 + lk * 8]);                      \
    _Pragma("unroll")                                                          \
    for (int fn = 0; fn < 4; ++fn) {                                           \
        oacc[fn] = mfma_bf16(pa0_, vb_[2 * fn], oacc[fn]);                     \
        oacc[fn] = mfma_bf16(pa1_, vb_[2 * fn + 1], oacc[fn]);                 \
    }                                                                          \
} while (0)

__global__ __launch_bounds__(128, 3)
void attn_kernel(const unsigned short* __restrict__ qws,
                 const unsigned short* __restrict__ kws,
                 const unsigned short* __restrict__ vT,
                 const float* __restrict__ B_graph,
                 const float* __restrict__ lattice,
                 const float* __restrict__ Wl,
                 const float* __restrict__ bl,
                 float* __restrict__ attn_out,
                 unsigned short* __restrict__ out_pre)
{
    const int n  = blockIdx.x;           // [0, 2048)
    const int bh = n & 31;
    const int tb = n >> 5;               // [0, 64)
    const int kg = tb >> 3, tt = tb & 7;
    const int ib = 8 * kg + ((kg & 1) ? 7 - tt : tt);
    const int b = bh >> 4, h = bh & 15;
    const int i0 = ib * 32;
    const int nj = (ib >> 1) + 1;

    __shared__ unsigned short Ps[2][2][16][72];   // [wave][parity][row][col]

    const int tid  = threadIdx.x;
    const int lane = tid & 63;
    const int w    = tid >> 6;
    const int l16  = lane & 15, lk = lane >> 4;

    float lb = bl[h];
#pragma unroll
    for (int t = 0; t < 6; ++t) lb += lattice[b * 6 + t] * Wl[t * HH + h];

    const int bhh = b * HH + h;
    const unsigned short* qbase = qws + ((size_t)bhh * LL + i0) * DHH;
    const unsigned short* kbase = kws + (size_t)bhh * LL * DHH;
    const unsigned short* vtb   = vT + (size_t)bhh * DHH * LL;
    const float* gb = B_graph + (size_t)b * LL * LL;

    bf16x8 qa0 = ld_frag(qbase + (size_t)(w * 16 + l16) * DHH + lk * 8);
    bf16x8 qa1 = ld_frag(qbase + (size_t)(w * 16 + l16) * DHH + 32 + lk * 8);

    const int gi0 = i0 + w * 16 + lk * 4;  // + r
    const float* gbrow = gb + (size_t)gi0 * LL;

    float s_run[4];
#pragma unroll
    for (int r = 0; r < 4; ++r) s_run[r] = 0.f;

    // -------- pass A: K double-buffered, peeled pair loop (R18 verbatim) ---
    {
        bf16x8 ka[8], kb[8];
        LOADK(ka, 0);
        int jb = 1;
        for (; jb + 1 < nj; jb += 2) {
            LOADK(kb, jb);
            ACCUMA(jb - 1, ka);
            LOADK(ka, jb + 1);
            ACCUMA(jb, kb);
        }
        if (jb < nj) {
            LOADK(kb, jb);
            ACCUMA(jb - 1, ka);
            ACCUMA(jb, kb);
        } else {
            ACCUMA(jb - 1, ka);
        }
    }
#pragma unroll
    for (int off = 1; off < 16; off <<= 1)
#pragma unroll
        for (int r = 0; r < 4; ++r) s_run[r] += __shfl_xor(s_run[r], off, 64);

    float inv_s[4];
#pragma unroll
    for (int r = 0; r < 4; ++r) inv_s[r] = 1.0f / s_run[r];

    f32x4 oacc[4];
#pragma unroll
    for (int fn = 0; fn < 4; ++fn) oacc[fn] = f32x4{0.f, 0.f, 0.f, 0.f};

    // -------- pass B: peeled pair loop, parity-indexed Ps buffers ----------
    {
        bf16x8 ka[8], kb[8];
        LOADK(ka, 0);
        int jb = 1;
        for (; jb + 1 < nj; jb += 2) {
            LOADK(kb, jb);
            PASSB_BODY(jb - 1, ka, 0);
            LOADK(ka, jb + 1);
            PASSB_BODY(jb, kb, 1);
        }
        if (jb < nj) {
            LOADK(kb, jb);
            PASSB_BODY(jb - 1, ka, 0);
            PASSB_BODY(jb, kb, 1);
        } else {
            PASSB_BODY(jb - 1, ka, 0);
        }
    }

    // zero-fill strictly-upper columns
    const int zc0 = nj * 64;
    if (zc0 < LL) {
        const int nz4 = (LL - zc0) >> 2;
        const f32x4 z4 = {0.f, 0.f, 0.f, 0.f};
        for (int row = 0; row < 32; ++row) {
            f32x4* zp = (f32x4*)(attn_out + ((size_t)bhh * LL + i0 + row) * LL + zc0);
            for (int c4 = tid; c4 < nz4; c4 += 128)
                __builtin_nontemporal_store(z4, &zp[c4]);
        }
    }

#pragma unroll
    for (int fn = 0; fn < 4; ++fn)
#pragma unroll
        for (int r = 0; r < 4; ++r) {
            const int gi = gi0 + r;
            const int d  = fn * 16 + l16;
            out_pre[((size_t)(b * LL + gi)) * NH + h * DHH + d] = f2bf(oacc[fn][r]);
        }
}

// ---------------------------------------------------------------------------
extern "C" void kernel_launch(void* const* d_in, const int* in_sizes, int n_in,
                              void* d_out, int out_size, void* d_ws, size_t ws_size,
                              hipStream_t stream)
{
    const float* x       = (const float*)d_in[0];
    const float* lattice = (const float*)d_in[1];
    const float* B_graph = (const float*)d_in[2];
    const float* Wq = (const float*)d_in[4];
    const float* bq = (const float*)d_in[5];
    const float* Wk = (const float*)d_in[6];
    const float* bk = (const float*)d_in[7];
    const float* Wv = (const float*)d_in[8];
    const float* bv = (const float*)d_in[9];
    const float* Wo = (const float*)d_in[10];
    const float* bo = (const float*)d_in[11];
    const float* Wl = (const float*)d_in[12];
    const float* bl = (const float*)d_in[13];

    float* out  = (float*)d_out;
    float* attn = out + (size_t)BB * LL * DD;

    const size_t PHL = (size_t)BB * HH * LL * DHH;
    unsigned short* qkv    = (unsigned short*)d_ws;
    unsigned short* qw     = qkv;
    unsigned short* kw     = qkv + PHL;
    unsigned short* vw     = qkv + 2 * PHL;
    unsigned short* outpre = qkv + 3 * PHL;
    unsigned short* Wqkvt  = outpre;                 // alias until attn runs
    unsigned short* xb     = outpre + (size_t)BB * LL * NH;
    unsigned short* vT     = xb;                     // alias after qkv GEMM
    unsigned short* Wot    = xb + (size_t)BB * LL * DD;

    conv_x_kernel<<<dim3((BB * LL * DD) / (256 * 8)), 256, 0, stream>>>(x, xb);
    conv_w_kernel<<<dim3(16, 16, 4), 256, 0, stream>>>(Wq, Wk, Wv, Wo, Wqkvt, Wot);

    gemm128_kernel<0><<<dim3(3 * NH / 128, (BB * LL) / 128), 256, 0, stream>>>(
        xb, Wqkvt, bq, bk, bv, qkv);

    v_transpose_kernel<<<dim3(LL / 64, BB * HH), 256, 0, stream>>>(vw, vT);

    attn_kernel<<<dim3(BB * HH * (LL / 32)), 128, 0, stream>>>(
        qw, kw, vT, B_graph, lattice, Wl, bl, attn, outpre);

    gemm128_kernel<1><<<dim3(DD / 128, (BB * LL) / 128), 256, 0, stream>>>(
        outpre, Wot, bo, bo, bo, out);
}

// Round 21
// 303.727 us; speedup vs baseline: 1.1396x; 1.0143x over previous
//
#include <hip/hip_runtime.h>
#include <stdint.h>
#include <stddef.h>

#define BB 2
#define LL 2048
#define DD 1024
#define HH 16
#define DHH 64
#define NH 1024  // H*DH

typedef __attribute__((ext_vector_type(8))) __bf16 bf16x8;
typedef __attribute__((ext_vector_type(4))) float f32x4;

__device__ __forceinline__ f32x4 mfma_bf16(bf16x8 a, bf16x8 b, f32x4 c) {
    return __builtin_amdgcn_mfma_f32_16x16x32_bf16(a, b, c, 0, 0, 0);
}

__device__ __forceinline__ unsigned short f2bf(float f) {
    union { float f; unsigned u; } v; v.f = f;
    unsigned r = v.u + 0x7FFFu + ((v.u >> 16) & 1u);  // RNE
    return (unsigned short)(r >> 16);
}

__device__ __forceinline__ float bf2f(unsigned short s) {
    union { unsigned u; float f; } v; v.u = ((unsigned)s) << 16;
    return v.f;
}

__device__ __forceinline__ bf16x8 ld_frag(const unsigned short* p) {
    return *reinterpret_cast<const bf16x8*>(p);
}

// ---------------------------------------------------------------------------
// x [4096][1024] fp32 -> bf16 flat.
// ---------------------------------------------------------------------------
__global__ __launch_bounds__(256)
void conv_x_kernel(const float* __restrict__ x, unsigned short* __restrict__ xb)
{
    const size_t i = ((size_t)blockIdx.x * 256 + threadIdx.x) * 8;
    float4 a = *(const float4*)(x + i);
    float4 b = *(const float4*)(x + i + 4);
    unsigned short t[8];
    t[0] = f2bf(a.x); t[1] = f2bf(a.y); t[2] = f2bf(a.z); t[3] = f2bf(a.w);
    t[4] = f2bf(b.x); t[5] = f2bf(b.y); t[6] = f2bf(b.z); t[7] = f2bf(b.w);
    *(int4*)(xb + i) = *(const int4*)t;
}

// ---------------------------------------------------------------------------
// W [K=1024][N=1024] fp32 -> W^T [N][K] bf16. blockIdx.z selects Wq/Wk/Wv/Wo.
// ---------------------------------------------------------------------------
__global__ __launch_bounds__(256)
void conv_w_kernel(const float* __restrict__ W0, const float* __restrict__ W1,
                   const float* __restrict__ W2, const float* __restrict__ W3,
                   unsigned short* __restrict__ Wqkvt,
                   unsigned short* __restrict__ Wot)
{
    __shared__ unsigned short Ls[64][72];
    const int which = blockIdx.z;
    const float* W = (which == 0) ? W0 : (which == 1) ? W1 : (which == 2) ? W2 : W3;
    unsigned short* Wt = (which == 3) ? Wot : (Wqkvt + (size_t)which * 1024 * 1024);

    const int kt = blockIdx.x * 64, nt = blockIdx.y * 64;
    const int tid = threadIdx.x;

    {
        const int r = tid >> 2, c = (tid & 3) * 16;
        const float* wp = W + (size_t)(kt + r) * 1024 + nt + c;
        unsigned short t[16];
#pragma unroll
        for (int q = 0; q < 4; ++q) {
            float4 f = *(const float4*)(wp + q * 4);
            t[q * 4 + 0] = f2bf(f.x); t[q * 4 + 1] = f2bf(f.y);
            t[q * 4 + 2] = f2bf(f.z); t[q * 4 + 3] = f2bf(f.w);
        }
        *(int4*)&Ls[r][c]     = *(const int4*)&t[0];
        *(int4*)&Ls[r][c + 8] = *(const int4*)&t[8];
    }
    __syncthreads();
    {
        const int nr = tid >> 2, kc = (tid & 3) * 16;
        unsigned short t[16];
#pragma unroll
        for (int m = 0; m < 16; ++m) t[m] = Ls[kc + m][nr];
        unsigned short* op = Wt + (size_t)(nt + nr) * 1024 + kt + kc;
        *(int4*)op       = *(const int4*)&t[0];
        *(int4*)(op + 8) = *(const int4*)&t[8];
    }
}

// ---------------------------------------------------------------------------
// 128x128 tile bf16 GEMM (K=1024, BK=64), A [M][K] bf16, Bt [N][K] bf16.
// MODE 0: qkv epilogue; MODE 1: out epilogue.
// ---------------------------------------------------------------------------
template<int MODE>
__global__ __launch_bounds__(256)
void gemm128_kernel(const unsigned short* __restrict__ A,
                    const unsigned short* __restrict__ Bt,
                    const float* __restrict__ b0, const float* __restrict__ b1,
                    const float* __restrict__ b2,
                    void* __restrict__ outp)
{
    __shared__ __align__(16) unsigned short As[128][64];
    __shared__ __align__(16) unsigned short Bs[128][64];

    const int tid  = threadIdx.x;
    const int lane = tid & 63;
    const int w    = tid >> 6;
    const int wr   = w >> 1, wc = w & 1;
    const int l16  = lane & 15, lk = lane >> 4;

    const int m0 = blockIdx.y * 128;
    const int n0 = blockIdx.x * 128;

    const int r8  = tid >> 3;
    const int cb  = tid & 7;
    const int swz = cb ^ (r8 & 7);

    const unsigned short* Ap = A  + (size_t)m0 * 1024 + cb * 8;
    const unsigned short* Bp = Bt + (size_t)n0 * 1024 + cb * 8;

    f32x4 acc[4][4];
#pragma unroll
    for (int i = 0; i < 4; ++i)
#pragma unroll
        for (int j = 0; j < 4; ++j) acc[i][j] = f32x4{0.f, 0.f, 0.f, 0.f};

    for (int k0 = 0; k0 < 1024; k0 += 64) {
        __syncthreads();
#pragma unroll
        for (int c = 0; c < 4; ++c) {
            const int row = c * 32 + r8;
            bf16x8 av = ld_frag(Ap + (size_t)row * 1024 + k0);
            bf16x8 bv = ld_frag(Bp + (size_t)row * 1024 + k0);
            *(bf16x8*)&As[row][swz * 8] = av;
            *(bf16x8*)&Bs[row][swz * 8] = bv;
        }
        __syncthreads();

#pragma unroll
        for (int kk = 0; kk < 2; ++kk) {
            bf16x8 af[4], bfr[4];
#pragma unroll
            for (int fm = 0; fm < 4; ++fm) {
                const int row = wr * 64 + fm * 16 + l16;
                const int kb  = kk * 4 + lk;
                af[fm] = ld_frag(&As[row][(kb ^ (row & 7)) * 8]);
            }
#pragma unroll
            for (int fn = 0; fn < 4; ++fn) {
                const int row = wc * 64 + fn * 16 + l16;
                const int kb  = kk * 4 + lk;
                bfr[fn] = ld_frag(&Bs[row][(kb ^ (row & 7)) * 8]);
            }
#pragma unroll
            for (int fm = 0; fm < 4; ++fm)
#pragma unroll
                for (int fn = 0; fn < 4; ++fn)
                    acc[fm][fn] = mfma_bf16(af[fm], bfr[fn], acc[fm][fn]);
        }
    }

    if (MODE == 0) {
        const int which = n0 >> 10;
        const float* bias = (which == 0) ? b0 : (which == 1) ? b1 : b2;
        unsigned short* out = (unsigned short*)outp
                            + (size_t)which * ((size_t)BB * HH * LL * DHH);
        const int c00 = n0 & 1023;
#pragma unroll
        for (int fm = 0; fm < 4; ++fm)
#pragma unroll
            for (int fn = 0; fn < 4; ++fn)
#pragma unroll
                for (int r = 0; r < 4; ++r) {
                    const int grow = m0 + wr * 64 + fm * 16 + lk * 4 + r;
                    const int c    = c00 + wc * 64 + fn * 16 + l16;
                    const float v  = acc[fm][fn][r] + bias[c];
                    const int b = grow >> 11, i = grow & 2047;
                    const int h = c >> 6,     d = c & 63;
                    out[(((size_t)(b * HH + h)) * LL + i) * DHH + d] = f2bf(v);
                }
    } else {
        float* out = (float*)outp;
#pragma unroll
        for (int fm = 0; fm < 4; ++fm)
#pragma unroll
            for (int fn = 0; fn < 4; ++fn)
#pragma unroll
                for (int r = 0; r < 4; ++r) {
                    const int grow = m0 + wr * 64 + fm * 16 + lk * 4 + r;
                    const int gcol = n0 + wc * 64 + fn * 16 + l16;
                    out[(size_t)grow * DD + gcol] = acc[fm][fn][r] + b0[gcol];
                }
    }
}

// ---------------------------------------------------------------------------
// V transpose: vws [bh][l][d] -> vT [bh][d][l].
// ---------------------------------------------------------------------------
__global__ __launch_bounds__(256)
void v_transpose_kernel(const unsigned short* __restrict__ vws,
                        unsigned short* __restrict__ vT)
{
    __shared__ unsigned short Ls[64][72];
    const int bh = blockIdx.y;
    const int i0 = blockIdx.x * 64;
    const int tid = threadIdx.x;

    {
        const int r = tid >> 2, c = (tid & 3) * 16;
        const unsigned short* vp = vws + ((size_t)bh * LL + i0 + r) * DHH + c;
        *(int4*)&Ls[r][c]     = *(const int4*)vp;
        *(int4*)&Ls[r][c + 8] = *(const int4*)(vp + 8);
    }
    __syncthreads();
    {
        const int d = tid >> 2, c = (tid & 3) * 16;
        unsigned short tmp[16];
#pragma unroll
        for (int m = 0; m < 16; ++m) tmp[m] = Ls[c + m][d];
        unsigned short* op = vT + ((size_t)bh * DHH + d) * LL + i0 + c;
        *(int4*)op       = *(const int4*)&tmp[0];
        *(int4*)(op + 8) = *(const int4*)&tmp[8];
    }
}

// ---------------------------------------------------------------------------
// Fused causal attention — EXACT R18 structure (best: 304.9 µs) plus T5:
// __builtin_amdgcn_s_setprio(1)/(0) wrapping the three MFMA clusters
// (pass-A QK, pass-B QK, PV). Independent blocks at different j-phases on
// each CU -> setprio lets MFMA-entering waves preempt load-issuing waves
// (guide m191: +4-7% on attn with this exact configuration class).
// QBLK=32, 128 threads (2 waves), zero barriers, balanced grid, max-free
// softmax, Ps-readback coalesced attn store, __launch_bounds__(128,3).
// ---------------------------------------------------------------------------

#define LOADK(KB, JB) do {                                                     \
    const unsigned short* kt_ = kbase + (size_t)(JB) * 64 * DHH;               \
    _Pragma("unroll")                                                          \
    for (int fn = 0; fn < 4; ++fn) {                                           \
        KB[2 * fn]     = ld_frag(kt_ + (size_t)(fn * 16 + l16) * DHH + lk * 8);\
        KB[2 * fn + 1] = ld_frag(kt_ + (size_t)(fn * 16 + l16) * DHH + 32 + lk * 8);\
    }                                                                          \
} while (0)

// pass-A accumulate for tile JB from buffer KB (R18 + setprio)
#define ACCUMA(JB, KB) do {                                                    \
    float g_[16];                                                              \
    _Pragma("unroll")                                                          \
    for (int fn = 0; fn < 4; ++fn) {                                           \
        const float* gp_ = gbrow + (JB) * 64 + fn * 16 + l16;                  \
        _Pragma("unroll")                                                      \
        for (int r = 0; r < 4; ++r) g_[fn * 4 + r] = gp_[(size_t)r * LL];      \
    }                                                                          \
    f32x4 z_[4];                                                               \
    __builtin_amdgcn_s_setprio(1);                                             \
    _Pragma("unroll")                                                          \
    for (int fn = 0; fn < 4; ++fn) {                                           \
        f32x4 z = {0.f, 0.f, 0.f, 0.f};                                        \
        z = mfma_bf16(qa0, KB[2 * fn], z);                                     \
        z = mfma_bf16(qa1, KB[2 * fn + 1], z);                                 \
        z_[fn] = z;                                                            \
    }                                                                          \
    __builtin_amdgcn_s_setprio(0);                                             \
    _Pragma("unroll")                                                          \
    for (int fn = 0; fn < 4; ++fn) {                                           \
        const int gj_ = (JB) * 64 + fn * 16 + l16;                             \
        _Pragma("unroll")                                                      \
        for (int r = 0; r < 4; ++r) {                                          \
            const float sv_ = fmaf(z_[fn][r], 0.125f, lb + g_[fn * 4 + r]);    \
            s_run[r] += (gj_ > gi0 + r) ? 0.f : __expf(sv_);                   \
        }                                                                      \
    }                                                                          \
} while (0)

// pass-B tile body (R18 + setprio). __VA_ARGS__ = K prefetch after QK MFMAs.
#define PASSB_BODY(JB, ...) do {                                               \
    bf16x8 vb_[8];                                                             \
    _Pragma("unroll")                                                          \
    for (int fn = 0; fn < 4; ++fn) {                                           \
        const unsigned short* vp_ = vtb + (size_t)(fn * 16 + l16) * LL + (JB) * 64;\
        vb_[2 * fn]     = ld_frag(vp_ + lk * 8);                               \
        vb_[2 * fn + 1] = ld_frag(vp_ + 32 + lk * 8);                          \
    }                                                                          \
    float g_[16];                                                              \
    _Pragma("unroll")                                                          \
    for (int fn = 0; fn < 4; ++fn) {                                           \
        const float* gp_ = gbrow + (JB) * 64 + fn * 16 + l16;                  \
        _Pragma("unroll")                                                      \
        for (int r = 0; r < 4; ++r) g_[fn * 4 + r] = gp_[(size_t)r * LL];      \
    }                                                                          \
    f32x4 z_[4];                                                               \
    __builtin_amdgcn_s_setprio(1);                                             \
    _Pragma("unroll")                                                          \
    for (int fn = 0; fn < 4; ++fn) {                                           \
        f32x4 z = {0.f, 0.f, 0.f, 0.f};                                        \
        z = mfma_bf16(qa0, ka[2 * fn], z);                                     \
        z = mfma_bf16(qa1, ka[2 * fn + 1], z);                                 \
        z_[fn] = z;                                                            \
    }                                                                          \
    __builtin_amdgcn_s_setprio(0);                                             \
    __VA_ARGS__;                                                               \
    _Pragma("unroll")                                                          \
    for (int fn = 0; fn < 4; ++fn) {                                           \
        const int gj_ = (JB) * 64 + fn * 16 + l16;                             \
        _Pragma("unroll")                                                      \
        for (int r = 0; r < 4; ++r) {                                          \
            const float sv_ = fmaf(z_[fn][r], 0.125f, lb + g_[fn * 4 + r]);    \
            const float p_ = ((gj_ > gi0 + r) ? 0.f : __expf(sv_)) * inv_s[r]; \
            Ps[w][lk * 4 + r][fn * 16 + l16] = f2bf(p_);                       \
        }                                                                      \
    }                                                                          \
    const int jc0_ = (JB) * 64 + l16 * 4;                                      \
    _Pragma("unroll")                                                          \
    for (int s = 0; s < 4; ++s) {                                              \
        const int row_ = s * 4 + lk;                                           \
        const int gi_  = i0 + w * 16 + row_;                                   \
        ushort4 pb_ = *(const ushort4*)&Ps[w][row_][l16 * 4];                  \
        f32x4 pv_;                                                             \
        pv_.x = bf2f(pb_.x); pv_.y = bf2f(pb_.y);                              \
        pv_.z = bf2f(pb_.z); pv_.w = bf2f(pb_.w);                              \
        __builtin_nontemporal_store(                                           \
            pv_, (f32x4*)&attn_out[((size_t)bhh * LL + gi_) * LL + jc0_]);     \
    }                                                                          \
    bf16x8 pa0_ = ld_frag(&Ps[w][l16][lk * 8]);                                \
    bf16x8 pa1_ = ld_frag(&Ps[w][l16][32 + lk * 8]);                           \
    __builtin_amdgcn_s_setprio(1);                                             \
    _Pragma("unroll")                                                          \
    for (int fn = 0; fn < 4; ++fn) {                                           \
        oacc[fn] = mfma_bf16(pa0_, vb_[2 * fn], oacc[fn]);                     \
        oacc[fn] = mfma_bf16(pa1_, vb_[2 * fn + 1], oacc[fn]);                 \
    }                                                                          \
    __builtin_amdgcn_s_setprio(0);                                             \
} while (0)

__global__ __launch_bounds__(128, 3)
void attn_kernel(const unsigned short* __restrict__ qws,
                 const unsigned short* __restrict__ kws,
                 const unsigned short* __restrict__ vT,
                 const float* __restrict__ B_graph,
                 const float* __restrict__ lattice,
                 const float* __restrict__ Wl,
                 const float* __restrict__ bl,
                 float* __restrict__ attn_out,
                 unsigned short* __restrict__ out_pre)
{
    const int n  = blockIdx.x;           // [0, 2048)
    const int bh = n & 31;
    const int tb = n >> 5;               // [0, 64)
    const int kg = tb >> 3, tt = tb & 7;
    const int ib = 8 * kg + ((kg & 1) ? 7 - tt : tt);
    const int b = bh >> 4, h = bh & 15;
    const int i0 = ib * 32;
    const int nj = (ib >> 1) + 1;

    __shared__ unsigned short Ps[2][16][72];

    const int tid  = threadIdx.x;
    const int lane = tid & 63;
    const int w    = tid >> 6;
    const int l16  = lane & 15, lk = lane >> 4;

    float lb = bl[h];
#pragma unroll
    for (int t = 0; t < 6; ++t) lb += lattice[b * 6 + t] * Wl[t * HH + h];

    const int bhh = b * HH + h;
    const unsigned short* qbase = qws + ((size_t)bhh * LL + i0) * DHH;
    const unsigned short* kbase = kws + (size_t)bhh * LL * DHH;
    const unsigned short* vtb   = vT + (size_t)bhh * DHH * LL;
    const float* gb = B_graph + (size_t)b * LL * LL;

    bf16x8 qa0 = ld_frag(qbase + (size_t)(w * 16 + l16) * DHH + lk * 8);
    bf16x8 qa1 = ld_frag(qbase + (size_t)(w * 16 + l16) * DHH + 32 + lk * 8);

    const int gi0 = i0 + w * 16 + lk * 4;  // + r
    const float* gbrow = gb + (size_t)gi0 * LL;

    float s_run[4];
#pragma unroll
    for (int r = 0; r < 4; ++r) s_run[r] = 0.f;

    // -------- pass A: K double-buffered, peeled pair loop --------
    {
        bf16x8 ka[8], kb[8];
        LOADK(ka, 0);
        int jb = 1;
        for (; jb + 1 < nj; jb += 2) {
            LOADK(kb, jb);
            ACCUMA(jb - 1, ka);
            LOADK(ka, jb + 1);
            ACCUMA(jb, kb);
        }
        if (jb < nj) {
            LOADK(kb, jb);
            ACCUMA(jb - 1, ka);
            ACCUMA(jb, kb);
        } else {
            ACCUMA(jb - 1, ka);
        }
    }
#pragma unroll
    for (int off = 1; off < 16; off <<= 1)
#pragma unroll
        for (int r = 0; r < 4; ++r) s_run[r] += __shfl_xor(s_run[r], off, 64);

    float inv_s[4];
#pragma unroll
    for (int r = 0; r < 4; ++r) inv_s[r] = 1.0f / s_run[r];

    f32x4 oacc[4];
#pragma unroll
    for (int fn = 0; fn < 4; ++fn) oacc[fn] = f32x4{0.f, 0.f, 0.f, 0.f};

    // -------- pass B: rotating single-buffer K prefetch --------
    {
        bf16x8 ka[8];
        LOADK(ka, 0);
        int jb = 0;
        for (; jb + 1 < nj; ++jb) {
            PASSB_BODY(jb, LOADK(ka, jb + 1));
        }
        PASSB_BODY(jb, );
    }

    // zero-fill strictly-upper columns
    const int zc0 = nj * 64;
    if (zc0 < LL) {
        const int nz4 = (LL - zc0) >> 2;
        const f32x4 z4 = {0.f, 0.f, 0.f, 0.f};
        for (int row = 0; row < 32; ++row) {
            f32x4* zp = (f32x4*)(attn_out + ((size_t)bhh * LL + i0 + row) * LL + zc0);
            for (int c4 = tid; c4 < nz4; c4 += 128)
                __builtin_nontemporal_store(z4, &zp[c4]);
        }
    }

#pragma unroll
    for (int fn = 0; fn < 4; ++fn)
#pragma unroll
        for (int r = 0; r < 4; ++r) {
            const int gi = gi0 + r;
            const int d  = fn * 16 + l16;
            out_pre[((size_t)(b * LL + gi)) * NH + h * DHH + d] = f2bf(oacc[fn][r]);
        }
}

// ---------------------------------------------------------------------------
extern "C" void kernel_launch(void* const* d_in, const int* in_sizes, int n_in,
                              void* d_out, int out_size, void* d_ws, size_t ws_size,
                              hipStream_t stream)
{
    const float* x       = (const float*)d_in[0];
    const float* lattice = (const float*)d_in[1];
    const float* B_graph = (const float*)d_in[2];
    const float* Wq = (const float*)d_in[4];
    const float* bq = (const float*)d_in[5];
    const float* Wk = (const float*)d_in[6];
    const float* bk = (const float*)d_in[7];
    const float* Wv = (const float*)d_in[8];
    const float* bv = (const float*)d_in[9];
    const float* Wo = (const float*)d_in[10];
    const float* bo = (const float*)d_in[11];
    const float* Wl = (const float*)d_in[12];
    const float* bl = (const float*)d_in[13];

    float* out  = (float*)d_out;
    float* attn = out + (size_t)BB * LL * DD;

    const size_t PHL = (size_t)BB * HH * LL * DHH;
    unsigned short* qkv    = (unsigned short*)d_ws;
    unsigned short* qw     = qkv;
    unsigned short* kw     = qkv + PHL;
    unsigned short* vw     = qkv + 2 * PHL;
    unsigned short* outpre = qkv + 3 * PHL;
    unsigned short* Wqkvt  = outpre;                 // alias until attn runs
    unsigned short* xb     = outpre + (size_t)BB * LL * NH;
    unsigned short* vT     = xb;                     // alias after qkv GEMM
    unsigned short* Wot    = xb + (size_t)BB * LL * DD;

    conv_x_kernel<<<dim3((BB * LL * DD) / (256 * 8)), 256, 0, stream>>>(x, xb);
    conv_w_kernel<<<dim3(16, 16, 4), 256, 0, stream>>>(Wq, Wk, Wv, Wo, Wqkvt, Wot);

    gemm128_kernel<0><<<dim3(3 * NH / 128, (BB * LL) / 128), 256, 0, stream>>>(
        xb, Wqkvt, bq, bk, bv, qkv);

    v_transpose_kernel<<<dim3(LL / 64, BB * HH), 256, 0, stream>>>(vw, vT);

    attn_kernel<<<dim3(BB * HH * (LL / 32)), 128, 0, stream>>>(
        qw, kw, vT, B_graph, lattice, Wl, bl, attn, outpre);

    gemm128_kernel<1><<<dim3(DD / 128, (BB * LL) / 128), 256, 0, stream>>>(
        outpre, Wot, bo, bo, bo, out);
}